// Round 6
// baseline (324.422 us; speedup 1.0000x reference)
//
#include <hip/hip_runtime.h>

#pragma clang fp contract(off)

#define NBOX 262144
#define NCLS 80
#define ROWS 85
#define CAP 1024
#define POOL 16384
#define VMAX 65536

typedef unsigned long long ull;

// ---------------- init
__global__ __launch_bounds__(64) void k_init(int* __restrict__ vcount,
                                             int* __restrict__ pool_count) {
    if (threadIdx.x == 0) { *vcount = 0; *pool_count = 0; }
}

// ---------------- stage1: wave-per-box, barrier-free, 1 atomic per wave
__global__ __launch_bounds__(256) void k_stage1(const float* __restrict__ det,
                                                int* __restrict__ vcount,
                                                int* __restrict__ cls_v,
                                                ull* __restrict__ key_v,
                                                float* __restrict__ conf_v,
                                                float4* __restrict__ box_v) {
    const int t = threadIdx.x, lane = t & 63;
    const int gw = (blockIdx.x * 256 + t) >> 6;   // 0..4095
    const int wbase = gw << 6;                    // 64 boxes per wave
    bool r_valid = false;
    int r_cls = 0;
    float r_conf = 0.f, r_score = 0.f, r_x1 = 0.f, r_y1 = 0.f, r_x2 = 0.f, r_y2 = 0.f;

    for (int i = 0; i < 64; i++) {
        const float* p = det + (long long)(wbase + i) * ROWS;
        float v1 = p[5 + lane];                   // classes 0..63, coalesced
        float aux = 0.0f;
        if (lane < 21) aux = p[(lane < 16) ? (69 + lane) : (lane - 16)];
        float mv = v1; int mi = lane;
        if (lane < 16 && aux > mv) { mv = aux; mi = 64 + lane; }  // cls 64..79, strict >
        #pragma unroll
        for (int off = 32; off; off >>= 1) {      // argmax, ties lowest idx
            float ov = __shfl_xor(mv, off);
            int oi = __shfl_xor(mi, off);
            if (ov > mv || (ov == mv && oi < mi)) { mv = ov; mi = oi; }
        }
        float xx = __shfl(aux, 16), yy = __shfl(aux, 17);
        float ww = __shfl(aux, 18), hh = __shfl(aux, 19);
        float obj = __shfl(aux, 20);
        if (lane == i) {                          // lane i owns box wbase+i
            r_valid = (obj >= 0.8f);              // CONF_THRES
            r_cls = mi; r_conf = mv; r_score = obj * mv;
            float hw = ww * 0.5f, hh2 = hh * 0.5f;
            r_x1 = xx - hw; r_y1 = yy - hh2; r_x2 = xx + hw; r_y2 = yy + hh2;
        }
    }
    ull bal = __ballot(r_valid);
    int cnt = (int)__popcll(bal);
    int base = 0;
    if (lane == 0 && cnt) base = atomicAdd(vcount, cnt);
    base = __shfl(base, 0);
    if (r_valid) {
        int pos = base + (int)__popcll(bal & ((1ull << lane) - 1ull));
        if (pos < VMAX) {
            cls_v[pos] = r_cls;
            key_v[pos] = ((ull)(~__float_as_uint(r_score)) << 32) | (unsigned)(wbase + lane);
            conf_v[pos] = r_conf;
            box_v[pos] = make_float4(r_x1, r_y1, r_x2, r_y2);
        }
    }
}

// ---------------- greedy pick loop, L slots/lane, all-register
template <int L>
__device__ __forceinline__ void pick_loop(ull (&k)[L], float4 (&bx)[L], float (&cf)[L],
                                          int lane, int& alive, int& np,
                                          ull* pkey, float* pconf, int stopAt) {
    while (alive > stopAt) {
        ull lm = k[0]; int lj = 0;
        #pragma unroll
        for (int j = 1; j < L; j++) if (k[j] < lm) { lm = k[j]; lj = j; }
        ull gm = lm;
        #pragma unroll
        for (int off = 32; off; off >>= 1) { ull o = __shfl_xor(gm, off); if (o < gm) gm = o; }
        if (gm == ~0ULL) { alive = 0; break; }
        float4 cb = bx[0]; float cc = cf[0];
        #pragma unroll
        for (int j = 1; j < L; j++) if (j == lj) { cb = bx[j]; cc = cf[j]; }
        ull wb = __ballot(lm == gm);              // unique winner (keys unique)
        int wl = (int)__ffsll((long long)wb) - 1;
        cb.x = __shfl(cb.x, wl); cb.y = __shfl(cb.y, wl);
        cb.z = __shfl(cb.z, wl); cb.w = __shfl(cb.w, wl);
        cc = __shfl(cc, wl);
        if (lane == 0) { pkey[np] = gm; pconf[np] = cc; }
        np++;
        float a1 = (cb.z - cb.x + 1.0f) * (cb.w - cb.y + 1.0f);
        int kills = 0;
        #pragma unroll
        for (int j = 0; j < L; j++) {
            if (k[j] != ~0ULL) {                  // winner self-kills via IoU=1
                float4 b = bx[j];
                float xx1 = fmaxf(cb.x, b.x), yy1 = fmaxf(cb.y, b.y);
                float xx2 = fminf(cb.z, b.z), yy2 = fminf(cb.w, b.w);
                float iw = xx2 - xx1 + 1.0f, ih = yy2 - yy1 + 1.0f;
                float inter = fmaxf(iw, 0.0f) * fmaxf(ih, 0.0f);
                float a2 = (b.z - b.x + 1.0f) * (b.w - b.y + 1.0f);
                float iou = inter / (a1 + a2 - inter + 1e-16f);
                if (iou > 0.4f) { k[j] = ~0ULL; kills++; }   // NMS_THRES
            }
        }
        #pragma unroll
        for (int off = 32; off; off >>= 1) kills += __shfl_xor(kills, off);
        alive -= kills;
    }
}

// ---------------- register compaction LF -> LT via LDS (single wave, no barriers)
template <int LF, int LT>
__device__ __forceinline__ void compact_regs(ull (&k)[LF], float4 (&bx)[LF], float (&cf)[LF],
                                             ull (&k2)[LT], float4 (&b2)[LT], float (&c2)[LT],
                                             int lane, int alive,
                                             ull* dk, float4* db, float* dc) {
    int ci = 0;
    #pragma unroll
    for (int j = 0; j < LF; j++) if (k[j] != ~0ULL) ci++;
    int inc = ci;
    for (int off = 1; off < 64; off <<= 1) {
        int o = __shfl_up(inc, off);
        if (lane >= off) inc += o;
    }
    int wp = inc - ci;
    #pragma unroll
    for (int j = 0; j < LF; j++)
        if (k[j] != ~0ULL) { dk[wp] = k[j]; db[wp] = bx[j]; dc[wp] = cf[j]; wp++; }
    #pragma unroll
    for (int j = 0; j < LT; j++) {
        int pos = lane + (j << 6);
        bool ok = pos < alive;
        k2[j] = ok ? dk[pos] : ~0ULL;
        b2[j] = ok ? db[pos] : make_float4(0.f, 0.f, 0.f, 0.f);
        c2[j] = ok ? dc[pos] : 0.0f;
    }
}

// ---------------- stage2+3: per-class compact + adaptive register greedy NMS
__global__ __launch_bounds__(512) void k_nms(const int* __restrict__ vcount,
                                             const int* __restrict__ cls_v,
                                             const ull* __restrict__ key_v,
                                             const float* __restrict__ conf_v,
                                             const float4* __restrict__ box_v,
                                             ull* __restrict__ pool_key,
                                             float* __restrict__ pool_conf,
                                             int* __restrict__ pool_cls,
                                             int* __restrict__ pool_count) {
    __shared__ ull skey[CAP];
    __shared__ float4 sbox[CAP];
    __shared__ float sconf[CAP];
    __shared__ ull pkey[CAP];
    __shared__ float pconf[CAP];
    __shared__ int s_n;
    const int c = blockIdx.x, t = threadIdx.x, lane = t & 63;
    const int total = min(*vcount, VMAX);
    if (t == 0) s_n = 0;
    for (int p = t; p < CAP; p += 512) skey[p] = ~0ULL;
    __syncthreads();

    for (int v0 = 0; v0 < total; v0 += 2048) {
        #pragma unroll
        for (int q = 0; q < 4; q++) {
            int v = v0 + (q << 9) + t;
            bool mm = (v < total) && (cls_v[v] == c);
            ull bal = __ballot(mm);
            if (bal) {
                int wb;
                if (lane == 0) wb = atomicAdd(&s_n, (int)__popcll(bal));
                wb = __shfl(wb, 0);
                if (mm) {
                    int pos = wb + (int)__popcll(bal & ((1ull << lane) - 1ull));
                    if (pos < CAP) {
                        skey[pos] = key_v[v];
                        sbox[pos] = box_v[v];
                        sconf[pos] = conf_v[v];
                    }
                }
            }
        }
    }
    __syncthreads();
    const int n = min(s_n, CAP);
    if (t >= 64) return;   // wave 0 only from here; no further barriers

    ull k16[16]; float4 b16[16]; float c16[16];
    #pragma unroll
    for (int j = 0; j < 16; j++) {
        int pos = lane + (j << 6);
        k16[j] = skey[pos];          // ~0ULL beyond n
        b16[j] = sbox[pos];          // junk beyond n, guarded by key==MAX
        c16[j] = sconf[pos];
    }
    int alive = n, np = 0;
    pick_loop<16>(k16, b16, c16, lane, alive, np, pkey, pconf, 256);
    ull k4[4]; float4 b4[4]; float c4[4];
    compact_regs<16, 4>(k16, b16, c16, k4, b4, c4, lane, alive, skey, sbox, sconf);
    pick_loop<4>(k4, b4, c4, lane, alive, np, pkey, pconf, 64);
    ull k1[1]; float4 b1[1]; float c1[1];
    compact_regs<4, 1>(k4, b4, c4, k1, b1, c1, lane, alive, skey, sbox, sconf);
    pick_loop<1>(k1, b1, c1, lane, alive, np, pkey, pconf, 0);

    int base = 0;
    if (lane == 0 && np) base = atomicAdd(pool_count, np);
    base = __shfl(base, 0);
    for (int j = lane; j < np; j += 64) {
        int pp = base + j;
        if (pp < POOL) {
            ull gm = pkey[j];
            // repack: bit63=0 | 31 score bits | 18 orig_idx | 14 pool_idx
            pool_key[pp] = ((ull)((unsigned)(gm >> 32) & 0x7FFFFFFFu) << 32)
                         | ((gm & 0xFFFFFFFFull) << 14) | (ull)pp;
            pool_conf[pp] = pconf[j];
            pool_cls[pp] = c;
        }
    }
}

// ---------------- single-wave in-register bitonic sort of 512 (8/lane, i = r*64+lane)
__device__ __forceinline__ void bsort512(ull (&x)[8], int lane) {
    #pragma unroll
    for (int k = 2; k <= 512; k <<= 1) {
        #pragma unroll
        for (int j = k >> 1; j >= 64; j >>= 1) {
            const int jr = j >> 6;
            #pragma unroll
            for (int r2 = 0; r2 < 8; r2++) {
                if ((r2 & jr) == 0) {
                    const bool asc = (((r2 << 6) & k) == 0);   // lane bits < 64 < k here
                    ull a = x[r2], b = x[r2 | jr];
                    if ((a > b) == asc) { x[r2] = b; x[r2 | jr] = a; }
                }
            }
        }
        #pragma unroll
        for (int j = ((k >> 1) > 32 ? 32 : (k >> 1)); j >= 1; j >>= 1) {
            #pragma unroll
            for (int r2 = 0; r2 < 8; r2++) {
                int i = (r2 << 6) + lane;
                bool asc = ((i & k) == 0);
                ull o = __shfl_xor(x[r2], j);
                bool lower = ((lane & j) == 0);
                ull mn = x[r2] < o ? x[r2] : o;
                ull mx2 = x[r2] < o ? o : x[r2];
                x[r2] = (asc == lower) ? mn : mx2;
            }
        }
    }
}

// ---------------- stage4: radix-select top-300 superset + single-wave sorts + output
__global__ __launch_bounds__(1024) void k_final(const ull* __restrict__ pool_key,
                                                const float* __restrict__ pool_conf,
                                                const int* __restrict__ pool_cls,
                                                const int* __restrict__ pool_count,
                                                float* __restrict__ out) {
    __shared__ int s_red[16];
    __shared__ int s_stat[2];
    __shared__ ull s_buf[512];
    __shared__ unsigned s_cb[512];
    __shared__ unsigned s_cl[512];
    const int t = threadIdx.x, wave = t >> 6, lane = t & 63;
    const int K = min(*pool_count, POOL);
    ull key[16];
    #pragma unroll
    for (int j = 0; j < 16; j++) {
        int pos = t + (j << 10);
        key[j] = (pos < K) ? pool_key[pos] : ~0ULL;   // valid keys have bit63=0
    }

    const bool selAll = (K <= 511);
    int bsh = 63; ull p = 0;
    if (!selAll) {
        // MSB radix binary search for the 300th-smallest key's prefix
        int r = 300, cand = K, b = 62;
        while (b >= 13 && cand > 212) {
            int c0 = 0;
            #pragma unroll
            for (int j = 0; j < 16; j++) {
                ull kk = key[j];
                if ((kk >> (b + 1)) == p && (((kk >> b) & 1ull) == 0)) c0++;
            }
            #pragma unroll
            for (int off = 32; off; off >>= 1) c0 += __shfl_xor(c0, off);
            if (lane == 0) s_red[wave] = c0;
            __syncthreads();
            if (t == 0) {
                int tot = 0;
                for (int w2 = 0; w2 < 16; w2++) tot += s_red[w2];
                s_stat[0] = tot;
            }
            __syncthreads();
            int cnt0 = s_stat[0];
            if (r <= cnt0) { cand = cnt0; p = p << 1; }
            else { r -= cnt0; cand -= cnt0; p = (p << 1) | 1ull; }
            b--;
        }
        bsh = b + 1;   // select set = {key >> bsh <= p}, size in [300, 511]
    }

    if (t == 0) s_stat[1] = 0;
    __syncthreads();
    int ci = 0;
    #pragma unroll
    for (int j = 0; j < 16; j++) {
        ull kk = key[j];
        bool sel = selAll ? ((kk >> 63) == 0) : ((kk >> bsh) <= p);
        if (sel) ci++;
    }
    int inc = ci;
    for (int off = 1; off < 64; off <<= 1) {
        int o = __shfl_up(inc, off);
        if (lane >= off) inc += o;
    }
    int wtot = __shfl(inc, 63);
    int wbase2 = 0;
    if (lane == 0 && wtot) wbase2 = atomicAdd(&s_stat[1], wtot);
    wbase2 = __shfl(wbase2, 0);
    int wp = wbase2 + inc - ci;
    #pragma unroll
    for (int j = 0; j < 16; j++) {
        ull kk = key[j];
        bool sel = selAll ? ((kk >> 63) == 0) : ((kk >> bsh) <= p);
        if (sel) s_buf[wp++] = kk;
    }
    __syncthreads();
    const int S = s_stat[1];
    if (t < 512 && t >= S) s_buf[t] = ~0ULL;
    __syncthreads();
    if (wave != 0) return;   // wave 0 finishes alone; no further barriers

    ull x[8];
    #pragma unroll
    for (int r2 = 0; r2 < 8; r2++) x[r2] = s_buf[(r2 << 6) + lane];
    bsort512(x, lane);       // rank i = sorted position = global pick rank

    ull y[8];
    #pragma unroll
    for (int r2 = 0; r2 < 8; r2++) {
        int i = (r2 << 6) + lane;
        ull kk = x[r2];
        ull k2 = ~0ULL;
        if (i < 300 && kk != ~0ULL) {
            int pidx = (int)(kk & 0x3FFFull);
            unsigned cb = __float_as_uint(pool_conf[pidx]);
            unsigned cl = (unsigned)pool_cls[pidx];
            s_cb[i] = cb; s_cl[i] = cl;
            k2 = ((ull)(~cb) << 32) | (unsigned)(~i);   // conf desc, ties rank desc
        }
        y[r2] = k2;
    }
    bsort512(y, lane);
    #pragma unroll
    for (int r2 = 0; r2 < 8; r2++) {
        int i = (r2 << 6) + lane;
        if (i < 300) {
            ull kk = y[r2];
            float idv = 0.0f, pv = 0.0f;
            if (kk != ~0ULL) {
                int slot = (int)(~(unsigned)(kk & 0xFFFFFFFFull));
                pv = __uint_as_float(s_cb[slot]);
                idv = (float)(int)s_cl[slot];
            }
            out[i] = idv;        // ids (1,300)
            out[300 + i] = pv;   // probs (300,)
        }
    }
}

extern "C" void kernel_launch(void* const* d_in, const int* in_sizes, int n_in,
                              void* d_out, int out_size, void* d_ws, size_t ws_size,
                              hipStream_t stream) {
    const float* det = (const float*)d_in[0];
    float* out = (float*)d_out;
    char* ws = (char*)d_ws;

    // workspace layout (~2.36 MB)
    int* vcount = (int*)(ws + 0);
    int* pool_count = (int*)(ws + 4);
    int* cls_v = (int*)(ws + 64);                 // VMAX*4 = 262144
    ull* key_v = (ull*)(ws + 262208);             // VMAX*8 = 524288
    float* conf_v = (float*)(ws + 786496);        // VMAX*4 = 262144
    float4* box_v = (float4*)(ws + 1048640);      // VMAX*16 = 1048576 (16B aligned)
    ull* pool_key = (ull*)(ws + 2097216);         // POOL*8 = 131072
    float* pool_conf = (float*)(ws + 2228288);    // POOL*4 = 65536
    int* pool_cls = (int*)(ws + 2293824);         // POOL*4 = 65536

    k_init<<<1, 64, 0, stream>>>(vcount, pool_count);
    k_stage1<<<1024, 256, 0, stream>>>(det, vcount, cls_v, key_v, conf_v, box_v);
    k_nms<<<NCLS, 512, 0, stream>>>(vcount, cls_v, key_v, conf_v, box_v,
                                    pool_key, pool_conf, pool_cls, pool_count);
    k_final<<<1, 1024, 0, stream>>>(pool_key, pool_conf, pool_cls, pool_count, out);
}

// Round 7
// 304.476 us; speedup vs baseline: 1.0655x; 1.0655x over previous
//
#include <hip/hip_runtime.h>

#pragma clang fp contract(off)

#define NBOX 262144
#define NCLS 80
#define ROWS 85
#define CAP 1024
#define POOL 16384
#define VMAX 65536
#define TB 64            // boxes per stage1 block
#define TF4 (TB * ROWS / 4)   // 1360 float4 per tile

typedef unsigned long long ull;

// ---------------- init
__global__ __launch_bounds__(64) void k_init(int* __restrict__ vcount,
                                             int* __restrict__ pool_count) {
    if (threadIdx.x == 0) { *vcount = 0; *pool_count = 0; }
}

// ---------------- stage1: tile->LDS, validity ballot, classify ONLY valid boxes
__global__ __launch_bounds__(256) void k_stage1(const float4* __restrict__ det4,
                                                int* __restrict__ vcount,
                                                int* __restrict__ cls_v,
                                                ull* __restrict__ key_v,
                                                float* __restrict__ conf_v,
                                                float4* __restrict__ box_v) {
    __shared__ float4 s4[TF4];          // 21,760 B
    __shared__ ull s_mask;
    __shared__ int s_base;
    __shared__ unsigned char wl[TB];    // worklist: valid box ids within tile
    float* s = (float*)s4;
    const int t = threadIdx.x;
    const long long base4 = (long long)blockIdx.x * TF4;

    // coalesced 16 B/lane staging (5.3 iters of 256 threads)
    for (int i = t; i < TF4; i += 256) s4[i] = det4[base4 + i];
    __syncthreads();

    // validity ballot: wave 0 (threads 0..63) covers the 64 boxes
    if (t < 64) {
        bool valid = (s[t * ROWS + 4] >= 0.8f);   // CONF_THRES
        ull m = __ballot(valid);
        if (t == 0) {
            s_mask = m;
            int nv = (int)__popcll(m);
            s_base = nv ? atomicAdd(vcount, nv) : 0;   // ONE global atomic per block
        }
        if (valid) {
            // rank within tile (no extra barrier needed before wl write)
            int r = (int)__popcll(m & ((1ull << t) - 1ull));
            wl[r] = (unsigned char)t;
        }
    }
    __syncthreads();
    const int nv = (int)__popcll(s_mask);
    const int base = s_base;

    // classify valid boxes only: pair (q = t>>1, sub = t&1), 2 threads/box
    const int q = t >> 1, sub = t & 1;
    if (q < nv) {
        const int b = wl[q];
        const float* p = s + b * ROWS;
        const int cbase = 5 + sub * 40;
        float mx = p[cbase];
        int am = sub * 40;
        #pragma unroll 8
        for (int j = 1; j < 40; j++) {
            float v = p[cbase + j];
            if (v > mx) { mx = v; am = sub * 40 + j; }   // strict > = first occurrence
        }
        float omx = __shfl_xor(mx, 1);
        int oam = __shfl_xor(am, 1);
        if (sub == 0) {
            if (omx > mx) { mx = omx; am = oam; }   // partner holds higher classes
            float x = p[0], y = p[1], w = p[2], h = p[3], obj = p[4];
            float hw = w * 0.5f, hh = h * 0.5f;
            float score = obj * mx;
            int gi = blockIdx.x * TB + b;
            int pos = base + q;
            if (pos < VMAX) {
                cls_v[pos] = am;
                key_v[pos] = ((ull)(~__float_as_uint(score)) << 32) | (unsigned)gi;
                conf_v[pos] = mx;
                box_v[pos] = make_float4(x - hw, y - hh, x + hw, y + hh);
            }
        }
    }
}

// ---------------- greedy pick loop, L slots/lane; alive via ballot (wave-uniform)
template <int L>
__device__ __forceinline__ void pick_loop(ull (&k)[L], float4 (&bx)[L], float (&cf)[L],
                                          int lane, int& alive, int& np,
                                          ull* pkey, float* pconf, int stopAt) {
    while (alive > stopAt) {
        ull lm = k[0]; int lj = 0;
        #pragma unroll
        for (int j = 1; j < L; j++) if (k[j] < lm) { lm = k[j]; lj = j; }
        ull gm = lm;
        #pragma unroll
        for (int off = 32; off; off >>= 1) { ull o = __shfl_xor(gm, off); if (o < gm) gm = o; }
        if (gm == ~0ULL) { alive = 0; break; }
        float4 cb = bx[0]; float cc = cf[0];
        #pragma unroll
        for (int j = 1; j < L; j++) if (j == lj) { cb = bx[j]; cc = cf[j]; }
        ull wb = __ballot(lm == gm);              // unique winner (keys unique)
        int wl2 = (int)__ffsll((long long)wb) - 1;
        cb.x = __shfl(cb.x, wl2); cb.y = __shfl(cb.y, wl2);
        cb.z = __shfl(cb.z, wl2); cb.w = __shfl(cb.w, wl2);
        cc = __shfl(cc, wl2);
        if (lane == 0) { pkey[np] = gm; pconf[np] = cc; }
        np++;
        float a1 = (cb.z - cb.x + 1.0f) * (cb.w - cb.y + 1.0f);
        #pragma unroll
        for (int j = 0; j < L; j++) {
            if (k[j] != ~0ULL) {                  // winner self-kills via IoU=1
                float4 b = bx[j];
                float xx1 = fmaxf(cb.x, b.x), yy1 = fmaxf(cb.y, b.y);
                float xx2 = fminf(cb.z, b.z), yy2 = fminf(cb.w, b.w);
                float iw = xx2 - xx1 + 1.0f, ih = yy2 - yy1 + 1.0f;
                float inter = fmaxf(iw, 0.0f) * fmaxf(ih, 0.0f);
                float a2 = (b.z - b.x + 1.0f) * (b.w - b.y + 1.0f);
                float iou = inter / (a1 + a2 - inter + 1e-16f);
                if (iou > 0.4f) k[j] = ~0ULL;     // NMS_THRES
            }
        }
        // recompute alive: L ballots, no shuffle chain
        int a = 0;
        #pragma unroll
        for (int j = 0; j < L; j++) a += (int)__popcll(__ballot(k[j] != ~0ULL));
        alive = a;
    }
}

// ---------------- register compaction LF -> LT via LDS (single wave, no barriers)
template <int LF, int LT>
__device__ __forceinline__ void compact_regs(ull (&k)[LF], float4 (&bx)[LF], float (&cf)[LF],
                                             ull (&k2)[LT], float4 (&b2)[LT], float (&c2)[LT],
                                             int lane, int alive,
                                             ull* dk, float4* db, float* dc) {
    int ci = 0;
    #pragma unroll
    for (int j = 0; j < LF; j++) if (k[j] != ~0ULL) ci++;
    int inc = ci;
    for (int off = 1; off < 64; off <<= 1) {
        int o = __shfl_up(inc, off);
        if (lane >= off) inc += o;
    }
    int wp = inc - ci;
    #pragma unroll
    for (int j = 0; j < LF; j++)
        if (k[j] != ~0ULL) { dk[wp] = k[j]; db[wp] = bx[j]; dc[wp] = cf[j]; wp++; }
    #pragma unroll
    for (int j = 0; j < LT; j++) {
        int pos = lane + (j << 6);
        bool ok = pos < alive;
        k2[j] = ok ? dk[pos] : ~0ULL;
        b2[j] = ok ? db[pos] : make_float4(0.f, 0.f, 0.f, 0.f);
        c2[j] = ok ? dc[pos] : 0.0f;
    }
}

// ---------------- stage2+3: per-class compact + adaptive register greedy NMS
__global__ __launch_bounds__(1024) void k_nms(const int* __restrict__ vcount,
                                              const int* __restrict__ cls_v,
                                              const ull* __restrict__ key_v,
                                              const float* __restrict__ conf_v,
                                              const float4* __restrict__ box_v,
                                              ull* __restrict__ pool_key,
                                              float* __restrict__ pool_conf,
                                              int* __restrict__ pool_cls,
                                              int* __restrict__ pool_count) {
    __shared__ ull skey[CAP];      // 8 KB
    __shared__ float4 sbox[CAP];   // 16 KB
    __shared__ float sconf[CAP];   // 4 KB
    __shared__ ull pkey[CAP];      // 8 KB
    __shared__ float pconf[CAP];   // 4 KB
    __shared__ int s_n;
    const int c = blockIdx.x, t = threadIdx.x, lane = t & 63;
    const int total = min(*vcount, VMAX);
    if (t == 0) s_n = 0;
    for (int p = t; p < CAP; p += 1024) skey[p] = ~0ULL;
    __syncthreads();

    // compaction: 1024 threads, 4 independent chunks/iter (13 L3-latency rounds)
    for (int v0 = 0; v0 < total; v0 += 4096) {
        #pragma unroll
        for (int qq = 0; qq < 4; qq++) {
            int v = v0 + (qq << 10) + t;
            bool mm = (v < total) && (cls_v[v] == c);
            ull bal = __ballot(mm);
            if (bal) {
                int wb;
                if (lane == 0) wb = atomicAdd(&s_n, (int)__popcll(bal));
                wb = __shfl(wb, 0);
                if (mm) {
                    int pos = wb + (int)__popcll(bal & ((1ull << lane) - 1ull));
                    if (pos < CAP) {
                        skey[pos] = key_v[v];
                        sbox[pos] = box_v[v];
                        sconf[pos] = conf_v[v];
                    }
                }
            }
        }
    }
    __syncthreads();
    const int n = min(s_n, CAP);
    if (t >= 64) return;   // wave 0 only from here; no further barriers

    ull k16[16]; float4 b16[16]; float c16[16];
    #pragma unroll
    for (int j = 0; j < 16; j++) {
        int pos = lane + (j << 6);
        k16[j] = skey[pos];          // ~0ULL beyond n
        b16[j] = sbox[pos];          // junk beyond n, guarded by key==MAX
        c16[j] = sconf[pos];
    }
    int alive = n, np = 0;
    pick_loop<16>(k16, b16, c16, lane, alive, np, pkey, pconf, 256);
    ull k4[4]; float4 b4[4]; float c4[4];
    compact_regs<16, 4>(k16, b16, c16, k4, b4, c4, lane, alive, skey, sbox, sconf);
    pick_loop<4>(k4, b4, c4, lane, alive, np, pkey, pconf, 64);
    ull k1[1]; float4 b1[1]; float c1[1];
    compact_regs<4, 1>(k4, b4, c4, k1, b1, c1, lane, alive, skey, sbox, sconf);
    pick_loop<1>(k1, b1, c1, lane, alive, np, pkey, pconf, 0);

    int base = 0;
    if (lane == 0 && np) base = atomicAdd(pool_count, np);
    base = __shfl(base, 0);
    for (int j = lane; j < np; j += 64) {
        int pp = base + j;
        if (pp < POOL) {
            ull gm = pkey[j];
            // repack: bit63=0 | 31 score bits | 18 orig_idx | 14 pool_idx
            pool_key[pp] = ((ull)((unsigned)(gm >> 32) & 0x7FFFFFFFu) << 32)
                         | ((gm & 0xFFFFFFFFull) << 14) | (ull)pp;
            pool_conf[pp] = pconf[j];
            pool_cls[pp] = c;
        }
    }
}

// ---------------- single-wave in-register bitonic sort of 512 (8/lane, i = r*64+lane)
__device__ __forceinline__ void bsort512(ull (&x)[8], int lane) {
    #pragma unroll
    for (int k = 2; k <= 512; k <<= 1) {
        #pragma unroll
        for (int j = k >> 1; j >= 64; j >>= 1) {
            const int jr = j >> 6;
            #pragma unroll
            for (int r2 = 0; r2 < 8; r2++) {
                if ((r2 & jr) == 0) {
                    const bool asc = (((r2 << 6) & k) == 0);
                    ull a = x[r2], b = x[r2 | jr];
                    if ((a > b) == asc) { x[r2] = b; x[r2 | jr] = a; }
                }
            }
        }
        #pragma unroll
        for (int j = ((k >> 1) > 32 ? 32 : (k >> 1)); j >= 1; j >>= 1) {
            #pragma unroll
            for (int r2 = 0; r2 < 8; r2++) {
                int i = (r2 << 6) + lane;
                bool asc = ((i & k) == 0);
                ull o = __shfl_xor(x[r2], j);
                bool lower = ((lane & j) == 0);
                ull mn = x[r2] < o ? x[r2] : o;
                ull mx2 = x[r2] < o ? o : x[r2];
                x[r2] = (asc == lower) ? mn : mx2;
            }
        }
    }
}

// ---------------- stage4: radix-select top-300 superset + single-wave sorts + output
__global__ __launch_bounds__(1024) void k_final(const ull* __restrict__ pool_key,
                                                const float* __restrict__ pool_conf,
                                                const int* __restrict__ pool_cls,
                                                const int* __restrict__ pool_count,
                                                float* __restrict__ out) {
    __shared__ int s_red[16];
    __shared__ int s_stat[2];
    __shared__ ull s_buf[512];
    __shared__ unsigned s_cb[512];
    __shared__ unsigned s_cl[512];
    const int t = threadIdx.x, wave = t >> 6, lane = t & 63;
    const int K = min(*pool_count, POOL);
    ull key[16];
    #pragma unroll
    for (int j = 0; j < 16; j++) {
        int pos = t + (j << 10);
        key[j] = (pos < K) ? pool_key[pos] : ~0ULL;   // valid keys have bit63=0
    }

    const bool selAll = (K <= 511);
    int bsh = 63; ull p = 0;
    if (!selAll) {
        int r = 300, cand = K, b = 62;
        while (b >= 13 && cand > 212) {
            int c0 = 0;
            #pragma unroll
            for (int j = 0; j < 16; j++) {
                ull kk = key[j];
                if ((kk >> (b + 1)) == p && (((kk >> b) & 1ull) == 0)) c0++;
            }
            #pragma unroll
            for (int off = 32; off; off >>= 1) c0 += __shfl_xor(c0, off);
            if (lane == 0) s_red[wave] = c0;
            __syncthreads();
            if (t == 0) {
                int tot = 0;
                for (int w2 = 0; w2 < 16; w2++) tot += s_red[w2];
                s_stat[0] = tot;
            }
            __syncthreads();
            int cnt0 = s_stat[0];
            if (r <= cnt0) { cand = cnt0; p = p << 1; }
            else { r -= cnt0; cand -= cnt0; p = (p << 1) | 1ull; }
            b--;
        }
        bsh = b + 1;   // select set = {key >> bsh <= p}, size in [300, 511]
    }

    if (t == 0) s_stat[1] = 0;
    __syncthreads();
    int ci = 0;
    #pragma unroll
    for (int j = 0; j < 16; j++) {
        ull kk = key[j];
        bool sel = selAll ? ((kk >> 63) == 0) : ((kk >> bsh) <= p);
        if (sel) ci++;
    }
    int inc = ci;
    for (int off = 1; off < 64; off <<= 1) {
        int o = __shfl_up(inc, off);
        if (lane >= off) inc += o;
    }
    int wtot = __shfl(inc, 63);
    int wbase2 = 0;
    if (lane == 0 && wtot) wbase2 = atomicAdd(&s_stat[1], wtot);
    wbase2 = __shfl(wbase2, 0);
    int wp = wbase2 + inc - ci;
    #pragma unroll
    for (int j = 0; j < 16; j++) {
        ull kk = key[j];
        bool sel = selAll ? ((kk >> 63) == 0) : ((kk >> bsh) <= p);
        if (sel) s_buf[wp++] = kk;
    }
    __syncthreads();
    const int S = s_stat[1];
    if (t < 512 && t >= S) s_buf[t] = ~0ULL;
    __syncthreads();
    if (wave != 0) return;   // wave 0 finishes alone

    ull x[8];
    #pragma unroll
    for (int r2 = 0; r2 < 8; r2++) x[r2] = s_buf[(r2 << 6) + lane];
    bsort512(x, lane);       // rank i = global pick rank

    ull y[8];
    #pragma unroll
    for (int r2 = 0; r2 < 8; r2++) {
        int i = (r2 << 6) + lane;
        ull kk = x[r2];
        ull k2 = ~0ULL;
        if (i < 300 && kk != ~0ULL) {
            int pidx = (int)(kk & 0x3FFFull);
            unsigned cb = __float_as_uint(pool_conf[pidx]);
            unsigned cl = (unsigned)pool_cls[pidx];
            s_cb[i] = cb; s_cl[i] = cl;
            k2 = ((ull)(~cb) << 32) | (unsigned)(~i);   // conf desc, ties rank desc
        }
        y[r2] = k2;
    }
    bsort512(y, lane);
    #pragma unroll
    for (int r2 = 0; r2 < 8; r2++) {
        int i = (r2 << 6) + lane;
        if (i < 300) {
            ull kk = y[r2];
            float idv = 0.0f, pv = 0.0f;
            if (kk != ~0ULL) {
                int slot = (int)(~(unsigned)(kk & 0xFFFFFFFFull));
                pv = __uint_as_float(s_cb[slot]);
                idv = (float)(int)s_cl[slot];
            }
            out[i] = idv;        // ids (1,300)
            out[300 + i] = pv;   // probs (300,)
        }
    }
}

extern "C" void kernel_launch(void* const* d_in, const int* in_sizes, int n_in,
                              void* d_out, int out_size, void* d_ws, size_t ws_size,
                              hipStream_t stream) {
    const float4* det4 = (const float4*)d_in[0];
    float* out = (float*)d_out;
    char* ws = (char*)d_ws;

    int* vcount = (int*)(ws + 0);
    int* pool_count = (int*)(ws + 4);
    int* cls_v = (int*)(ws + 64);                 // VMAX*4 = 262144
    ull* key_v = (ull*)(ws + 262208);             // VMAX*8 = 524288
    float* conf_v = (float*)(ws + 786496);        // VMAX*4 = 262144
    float4* box_v = (float4*)(ws + 1048640);      // VMAX*16 = 1048576 (16B aligned)
    ull* pool_key = (ull*)(ws + 2097216);         // POOL*8 = 131072
    float* pool_conf = (float*)(ws + 2228288);    // POOL*4 = 65536
    int* pool_cls = (int*)(ws + 2293824);         // POOL*4 = 65536

    k_init<<<1, 64, 0, stream>>>(vcount, pool_count);
    k_stage1<<<NBOX / TB, 256, 0, stream>>>(det4, vcount, cls_v, key_v, conf_v, box_v);
    k_nms<<<NCLS, 1024, 0, stream>>>(vcount, cls_v, key_v, conf_v, box_v,
                                     pool_key, pool_conf, pool_cls, pool_count);
    k_final<<<1, 1024, 0, stream>>>(pool_key, pool_conf, pool_cls, pool_count, out);
}

// Round 8
// 249.727 us; speedup vs baseline: 1.2991x; 1.2192x over previous
//
#include <hip/hip_runtime.h>

#pragma clang fp contract(off)

#define NBOX 262144
#define NCLS 80
#define ROWS 85
#define CAP 1024
#define POOL 8192
#define VMAX 65536
#define TB 64            // boxes per stage1 block
#define TF4 (TB * ROWS / 4)   // 1360 float4 per tile

typedef unsigned long long ull;

// ---------------- init
__global__ __launch_bounds__(64) void k_init(int* __restrict__ vcount,
                                             int* __restrict__ pool_count) {
    if (threadIdx.x == 0) { *vcount = 0; *pool_count = 0; }
}

// ---------------- stage1: tile->LDS, validity ballot, classify ONLY valid boxes
__global__ __launch_bounds__(256) void k_stage1(const float4* __restrict__ det4,
                                                int* __restrict__ vcount,
                                                int* __restrict__ cls_v,
                                                ull* __restrict__ key_v,
                                                float* __restrict__ conf_v,
                                                float4* __restrict__ box_v) {
    __shared__ float4 s4[TF4];          // 21,760 B
    __shared__ ull s_mask;
    __shared__ int s_base;
    __shared__ unsigned char wl[TB];    // worklist: valid box ids within tile
    float* s = (float*)s4;
    const int t = threadIdx.x;
    const long long base4 = (long long)blockIdx.x * TF4;

    for (int i = t; i < TF4; i += 256) s4[i] = det4[base4 + i];
    __syncthreads();

    if (t < 64) {
        bool valid = (s[t * ROWS + 4] >= 0.8f);   // CONF_THRES
        ull m = __ballot(valid);
        if (t == 0) {
            s_mask = m;
            int nv = (int)__popcll(m);
            s_base = nv ? atomicAdd(vcount, nv) : 0;   // ONE global atomic per block
        }
        if (valid) {
            int r = (int)__popcll(m & ((1ull << t) - 1ull));
            wl[r] = (unsigned char)t;
        }
    }
    __syncthreads();
    const int nv = (int)__popcll(s_mask);
    const int base = s_base;

    const int q = t >> 1, sub = t & 1;
    if (q < nv) {
        const int b = wl[q];
        const float* p = s + b * ROWS;
        const int cbase = 5 + sub * 40;
        float mx = p[cbase];
        int am = sub * 40;
        #pragma unroll 8
        for (int j = 1; j < 40; j++) {
            float v = p[cbase + j];
            if (v > mx) { mx = v; am = sub * 40 + j; }   // strict > = first occurrence
        }
        float omx = __shfl_xor(mx, 1);
        int oam = __shfl_xor(am, 1);
        if (sub == 0) {
            if (omx > mx) { mx = omx; am = oam; }   // partner holds higher classes
            float x = p[0], y = p[1], w = p[2], h = p[3], obj = p[4];
            float hw = w * 0.5f, hh = h * 0.5f;
            float score = obj * mx;
            int gi = blockIdx.x * TB + b;
            int pos = base + q;
            if (pos < VMAX) {
                cls_v[pos] = am;
                key_v[pos] = ((ull)(~__float_as_uint(score)) << 32) | (unsigned)gi;
                conf_v[pos] = mx;
                box_v[pos] = make_float4(x - hw, y - hh, x + hw, y + hh);
            }
        }
    }
}

// ---------------- exact alive count (wave-uniform)
template <int L>
__device__ __forceinline__ int exact_alive(ull (&k)[L]) {
    int a = 0;
    #pragma unroll
    for (int j = 0; j < L; j++) a += (int)__popcll(__ballot(k[j] != ~0ULL));
    return a;
}

// ---------------- greedy pick loop; alive refreshed every 8 picks only
template <int L>
__device__ __forceinline__ void pick_loop(ull (&k)[L], float4 (&bx)[L], float (&cf)[L],
                                          int lane, int& alive, int& np,
                                          ull* pkey, float* pconf, int stopAt) {
    while (alive > stopAt) {
        ull lm = k[0]; int lj = 0;
        #pragma unroll
        for (int j = 1; j < L; j++) if (k[j] < lm) { lm = k[j]; lj = j; }
        ull gm = lm;
        #pragma unroll
        for (int off = 32; off; off >>= 1) { ull o = __shfl_xor(gm, off); if (o < gm) gm = o; }
        if (gm == ~0ULL) { alive = 0; break; }
        float4 cb = bx[0]; float cc = cf[0];
        #pragma unroll
        for (int j = 1; j < L; j++) if (j == lj) { cb = bx[j]; cc = cf[j]; }
        ull wb = __ballot(lm == gm);              // unique winner (keys unique)
        int wl2 = (int)__ffsll((long long)wb) - 1;
        cb.x = __shfl(cb.x, wl2); cb.y = __shfl(cb.y, wl2);
        cb.z = __shfl(cb.z, wl2); cb.w = __shfl(cb.w, wl2);
        cc = __shfl(cc, wl2);
        if (lane == 0) { pkey[np] = gm; pconf[np] = cc; }
        np++;
        float a1 = (cb.z - cb.x + 1.0f) * (cb.w - cb.y + 1.0f);
        #pragma unroll
        for (int j = 0; j < L; j++) {
            if (k[j] != ~0ULL) {                  // winner self-kills via IoU=1
                float4 b = bx[j];
                float xx1 = fmaxf(cb.x, b.x), yy1 = fmaxf(cb.y, b.y);
                float xx2 = fminf(cb.z, b.z), yy2 = fminf(cb.w, b.w);
                float iw = xx2 - xx1 + 1.0f, ih = yy2 - yy1 + 1.0f;
                float inter = fmaxf(iw, 0.0f) * fmaxf(ih, 0.0f);
                float a2 = (b.z - b.x + 1.0f) * (b.w - b.y + 1.0f);
                float iou = inter / (a1 + a2 - inter + 1e-16f);
                if (iou > 0.4f) k[j] = ~0ULL;     // NMS_THRES
            }
        }
        if ((np & 7) == 0) alive = exact_alive(k);   // cheap refresh; stale-high is safe
    }
}

// ---------------- register compaction LF -> LT via LDS (single wave; alive EXACT)
template <int LF, int LT>
__device__ __forceinline__ void compact_regs(ull (&k)[LF], float4 (&bx)[LF], float (&cf)[LF],
                                             ull (&k2)[LT], float4 (&b2)[LT], float (&c2)[LT],
                                             int lane, int alive,
                                             ull* dk, float4* db, float* dc) {
    int ci = 0;
    #pragma unroll
    for (int j = 0; j < LF; j++) if (k[j] != ~0ULL) ci++;
    int inc = ci;
    for (int off = 1; off < 64; off <<= 1) {
        int o = __shfl_up(inc, off);
        if (lane >= off) inc += o;
    }
    int wp = inc - ci;
    #pragma unroll
    for (int j = 0; j < LF; j++)
        if (k[j] != ~0ULL) { dk[wp] = k[j]; db[wp] = bx[j]; dc[wp] = cf[j]; wp++; }
    #pragma unroll
    for (int j = 0; j < LT; j++) {
        int pos = lane + (j << 6);
        bool ok = pos < alive;
        k2[j] = ok ? dk[pos] : ~0ULL;
        b2[j] = ok ? db[pos] : make_float4(0.f, 0.f, 0.f, 0.f);
        c2[j] = ok ? dc[pos] : 0.0f;
    }
}

// ---------------- stage2+3: per-class compact + adaptive register greedy NMS
__global__ __launch_bounds__(1024) void k_nms(const int* __restrict__ vcount,
                                              const int* __restrict__ cls_v,
                                              const ull* __restrict__ key_v,
                                              const float* __restrict__ conf_v,
                                              const float4* __restrict__ box_v,
                                              ull* __restrict__ pool_key,
                                              float* __restrict__ pool_conf,
                                              int* __restrict__ pool_cls,
                                              int* __restrict__ pool_count) {
    __shared__ ull skey[CAP];
    __shared__ float4 sbox[CAP];
    __shared__ float sconf[CAP];
    __shared__ ull pkey[CAP];
    __shared__ float pconf[CAP];
    __shared__ int s_n;
    const int c = blockIdx.x, t = threadIdx.x, lane = t & 63;
    const int total = min(*vcount, VMAX);
    if (t == 0) s_n = 0;
    for (int p = t; p < CAP; p += 1024) skey[p] = ~0ULL;
    __syncthreads();

    for (int v0 = 0; v0 < total; v0 += 4096) {
        #pragma unroll
        for (int qq = 0; qq < 4; qq++) {
            int v = v0 + (qq << 10) + t;
            bool mm = (v < total) && (cls_v[v] == c);
            ull bal = __ballot(mm);
            if (bal) {
                int wb;
                if (lane == 0) wb = atomicAdd(&s_n, (int)__popcll(bal));
                wb = __shfl(wb, 0);
                if (mm) {
                    int pos = wb + (int)__popcll(bal & ((1ull << lane) - 1ull));
                    if (pos < CAP) {
                        skey[pos] = key_v[v];
                        sbox[pos] = box_v[v];
                        sconf[pos] = conf_v[v];
                    }
                }
            }
        }
    }
    __syncthreads();
    const int n = min(s_n, CAP);
    if (t >= 64) return;   // wave 0 only from here; no further barriers

    ull k16[16]; float4 b16[16]; float c16[16];
    #pragma unroll
    for (int j = 0; j < 16; j++) {
        int pos = lane + (j << 6);
        k16[j] = skey[pos];
        b16[j] = sbox[pos];
        c16[j] = sconf[pos];
    }
    int alive = n, np = 0;
    pick_loop<16>(k16, b16, c16, lane, alive, np, pkey, pconf, 256);
    alive = exact_alive(k16);                       // exact before compaction
    ull k4[4]; float4 b4[4]; float c4[4];
    compact_regs<16, 4>(k16, b16, c16, k4, b4, c4, lane, alive, skey, sbox, sconf);
    pick_loop<4>(k4, b4, c4, lane, alive, np, pkey, pconf, 64);
    alive = exact_alive(k4);
    ull k1[1]; float4 b1[1]; float c1[1];
    compact_regs<4, 1>(k4, b4, c4, k1, b1, c1, lane, alive, skey, sbox, sconf);
    pick_loop<1>(k1, b1, c1, lane, alive, np, pkey, pconf, 0);

    // cap at 300/class (exact: picks are in ascending key order)
    int npw = min(np, 300);
    int base = 0;
    if (lane == 0 && npw) base = atomicAdd(pool_count, npw);
    base = __shfl(base, 0);
    for (int j = lane; j < npw; j += 64) {
        int pp = base + j;
        if (pp < POOL) {
            ull gm = pkey[j];
            // repack: bit63=0 | 31 score bits | 18 orig_idx | 14 pool_idx
            pool_key[pp] = ((ull)((unsigned)(gm >> 32) & 0x7FFFFFFFu) << 32)
                         | ((gm & 0xFFFFFFFFull) << 14) | (ull)pp;
            pool_conf[pp] = pconf[j];
            pool_cls[pp] = c;
        }
    }
}

// ---------------- single-wave in-register bitonic sort of 512 (8/lane, i = r*64+lane)
__device__ __forceinline__ void bsort512(ull (&x)[8], int lane) {
    #pragma unroll
    for (int k = 2; k <= 512; k <<= 1) {
        #pragma unroll
        for (int j = k >> 1; j >= 64; j >>= 1) {
            const int jr = j >> 6;
            #pragma unroll
            for (int r2 = 0; r2 < 8; r2++) {
                if ((r2 & jr) == 0) {
                    const bool asc = (((r2 << 6) & k) == 0);
                    ull a = x[r2], b = x[r2 | jr];
                    if ((a > b) == asc) { x[r2] = b; x[r2 | jr] = a; }
                }
            }
        }
        #pragma unroll
        for (int j = ((k >> 1) > 32 ? 32 : (k >> 1)); j >= 1; j >>= 1) {
            #pragma unroll
            for (int r2 = 0; r2 < 8; r2++) {
                int i = (r2 << 6) + lane;
                bool asc = ((i & k) == 0);
                ull o = __shfl_xor(x[r2], j);
                bool lower = ((lane & j) == 0);
                ull mn = x[r2] < o ? x[r2] : o;
                ull mx2 = x[r2] < o ? o : x[r2];
                x[r2] = (asc == lower) ? mn : mx2;
            }
        }
    }
}

// ---------------- stage4: 256-thread radix-select + single-wave 2-pass sort + output
__global__ __launch_bounds__(256) void k_final(const ull* __restrict__ pool_key,
                                               const float* __restrict__ pool_conf,
                                               const int* __restrict__ pool_cls,
                                               const int* __restrict__ pool_count,
                                               float* __restrict__ out) {
    __shared__ int s_red[4];
    __shared__ int s_stat[2];
    __shared__ ull s_buf[512];
    __shared__ unsigned s_cb[512];
    __shared__ unsigned s_cl[512];
    const int t = threadIdx.x, wave = t >> 6, lane = t & 63;
    const int K = min(*pool_count, POOL);
    ull key[32];   // 8192 keys over 256 threads
    #pragma unroll
    for (int j = 0; j < 32; j++) {
        int pos = t + (j << 8);
        key[j] = (pos < K) ? pool_key[pos] : ~0ULL;   // valid keys have bit63=0
    }

    const bool selAll = (K <= 511);
    int bsh = 63; ull p = 0;
    if (!selAll) {
        int r = 300, cand = K, b = 62;
        while (b >= 13 && cand > 212) {
            int c0 = 0;
            #pragma unroll
            for (int j = 0; j < 32; j++) {
                ull kk = key[j];
                if ((kk >> (b + 1)) == p && (((kk >> b) & 1ull) == 0)) c0++;
            }
            #pragma unroll
            for (int off = 32; off; off >>= 1) c0 += __shfl_xor(c0, off);
            if (lane == 0) s_red[wave] = c0;
            __syncthreads();
            if (t == 0) s_stat[0] = s_red[0] + s_red[1] + s_red[2] + s_red[3];
            __syncthreads();
            int cnt0 = s_stat[0];
            if (r <= cnt0) { cand = cnt0; p = p << 1; }
            else { r -= cnt0; cand -= cnt0; p = (p << 1) | 1ull; }
            b--;
        }
        bsh = b + 1;   // select set = {key >> bsh <= p}, size in [300, 511]
    }

    if (t == 0) s_stat[1] = 0;
    __syncthreads();
    int ci = 0;
    #pragma unroll
    for (int j = 0; j < 32; j++) {
        ull kk = key[j];
        bool sel = selAll ? ((kk >> 63) == 0) : ((kk >> bsh) <= p);
        if (sel) ci++;
    }
    int inc = ci;
    for (int off = 1; off < 64; off <<= 1) {
        int o = __shfl_up(inc, off);
        if (lane >= off) inc += o;
    }
    int wtot = __shfl(inc, 63);
    int wbase2 = 0;
    if (lane == 0 && wtot) wbase2 = atomicAdd(&s_stat[1], wtot);
    wbase2 = __shfl(wbase2, 0);
    int wp = wbase2 + inc - ci;
    #pragma unroll
    for (int j = 0; j < 32; j++) {
        ull kk = key[j];
        bool sel = selAll ? ((kk >> 63) == 0) : ((kk >> bsh) <= p);
        if (sel) s_buf[wp++] = kk;
    }
    __syncthreads();
    const int S = s_stat[1];
    for (int i = t; i < 512; i += 256) if (i >= S) s_buf[i] = ~0ULL;
    __syncthreads();
    if (wave != 0) return;   // wave 0 finishes alone; no further barriers

    // two sorts through ONE bsort512 instantiation (code-size control)
    #pragma clang loop unroll(disable)
    for (int pass = 0; pass < 2; pass++) {
        ull x[8];
        #pragma unroll
        for (int r2 = 0; r2 < 8; r2++) x[r2] = s_buf[(r2 << 6) + lane];
        bsort512(x, lane);
        if (pass == 0) {
            // rank i = global pick rank; build conf-resort keys in s_buf
            #pragma unroll
            for (int r2 = 0; r2 < 8; r2++) {
                int i = (r2 << 6) + lane;
                ull kk = x[r2];
                ull k2 = ~0ULL;
                if (i < 300 && kk != ~0ULL) {
                    int pidx = (int)(kk & 0x3FFFull);
                    unsigned cb = __float_as_uint(pool_conf[pidx]);
                    unsigned cl = (unsigned)pool_cls[pidx];
                    s_cb[i] = cb; s_cl[i] = cl;
                    k2 = ((ull)(~cb) << 32) | (unsigned)(~i);   // conf desc, rank desc
                }
                s_buf[i] = k2;
            }
        } else {
            #pragma unroll
            for (int r2 = 0; r2 < 8; r2++) {
                int i = (r2 << 6) + lane;
                if (i < 300) {
                    ull kk = x[r2];
                    float idv = 0.0f, pv = 0.0f;
                    if (kk != ~0ULL) {
                        int slot = (int)(~(unsigned)(kk & 0xFFFFFFFFull));
                        pv = __uint_as_float(s_cb[slot]);
                        idv = (float)(int)s_cl[slot];
                    }
                    out[i] = idv;        // ids (1,300)
                    out[300 + i] = pv;   // probs (300,)
                }
            }
        }
    }
}

extern "C" void kernel_launch(void* const* d_in, const int* in_sizes, int n_in,
                              void* d_out, int out_size, void* d_ws, size_t ws_size,
                              hipStream_t stream) {
    const float4* det4 = (const float4*)d_in[0];
    float* out = (float*)d_out;
    char* ws = (char*)d_ws;

    int* vcount = (int*)(ws + 0);
    int* pool_count = (int*)(ws + 4);
    int* cls_v = (int*)(ws + 64);                 // VMAX*4 = 262144
    ull* key_v = (ull*)(ws + 262208);             // VMAX*8 = 524288
    float* conf_v = (float*)(ws + 786496);        // VMAX*4 = 262144
    float4* box_v = (float4*)(ws + 1048640);      // VMAX*16 = 1048576 (16B aligned)
    ull* pool_key = (ull*)(ws + 2097216);         // POOL*8 = 65536
    float* pool_conf = (float*)(ws + 2162752);    // POOL*4 = 32768
    int* pool_cls = (int*)(ws + 2195520);         // POOL*4 = 32768

    k_init<<<1, 64, 0, stream>>>(vcount, pool_count);
    k_stage1<<<NBOX / TB, 256, 0, stream>>>(det4, vcount, cls_v, key_v, conf_v, box_v);
    k_nms<<<NCLS, 1024, 0, stream>>>(vcount, cls_v, key_v, conf_v, box_v,
                                     pool_key, pool_conf, pool_cls, pool_count);
    k_final<<<1, 256, 0, stream>>>(pool_key, pool_conf, pool_cls, pool_count, out);
}

// Round 9
// 228.952 us; speedup vs baseline: 1.4170x; 1.0907x over previous
//
#include <hip/hip_runtime.h>

#pragma clang fp contract(off)

#define NBOX 262144
#define NCLS 80
#define ROWS 85
#define CAP 1024
#define POOL 8192
#define VMAX 65536
#define TB 64                 // boxes per stage1 tile
#define TF4 (TB * ROWS / 4)   // 1360 useful float4 per tile
#define TLOAD 1536            // padded staging count (6 x 256), spills into next tile
#define NF4 (NBOX * ROWS / 4) // 5,570,560 float4 total

typedef unsigned long long ull;

// ---------------- init
__global__ __launch_bounds__(64) void k_init(int* __restrict__ vcount,
                                             int* __restrict__ pool_count) {
    if (threadIdx.x == 0) { *vcount = 0; *pool_count = 0; }
}

// ---------------- stage1: 6-deep unrolled burst staging + classify valid boxes only
__global__ __launch_bounds__(256) void k_stage1(const float4* __restrict__ det4,
                                                int* __restrict__ vcount,
                                                int* __restrict__ cls_v,
                                                ull* __restrict__ key_v,
                                                float* __restrict__ conf_v,
                                                float4* __restrict__ box_v) {
    __shared__ float4 s4[TLOAD];        // 24,576 B -> 6 blocks/CU
    __shared__ ull s_mask;
    __shared__ int s_base;
    __shared__ unsigned char wl[TB];
    float* s = (float*)s4;
    const int t = threadIdx.x;
    const int base4 = blockIdx.x * TF4;

    // 6 independent loads in flight, then 6 LDS writes (no per-iter waitcnt chain)
    const int i0 = base4 + t;
    float4 r0 = det4[min(i0,          NF4 - 1)];
    float4 r1 = det4[min(i0 + 256,    NF4 - 1)];
    float4 r2 = det4[min(i0 + 512,    NF4 - 1)];
    float4 r3 = det4[min(i0 + 768,    NF4 - 1)];
    float4 r4 = det4[min(i0 + 1024,   NF4 - 1)];
    float4 r5 = det4[min(i0 + 1280,   NF4 - 1)];
    s4[t]        = r0;
    s4[t + 256]  = r1;
    s4[t + 512]  = r2;
    s4[t + 768]  = r3;
    s4[t + 1024] = r4;
    s4[t + 1280] = r5;
    __syncthreads();

    if (t < 64) {
        bool valid = (s[t * ROWS + 4] >= 0.8f);   // CONF_THRES
        ull m = __ballot(valid);
        if (t == 0) {
            s_mask = m;
            int nv = (int)__popcll(m);
            s_base = nv ? atomicAdd(vcount, nv) : 0;   // ONE global atomic per block
        }
        if (valid) {
            int r = (int)__popcll(m & ((1ull << t) - 1ull));
            wl[r] = (unsigned char)t;
        }
    }
    __syncthreads();
    const int nv = (int)__popcll(s_mask);
    const int base = s_base;

    const int q = t >> 1, sub = t & 1;
    if (q < nv) {
        const int b = wl[q];
        const float* p = s + b * ROWS;
        const int cbase = 5 + sub * 40;
        float mx = p[cbase];
        int am = sub * 40;
        #pragma unroll 8
        for (int j = 1; j < 40; j++) {
            float v = p[cbase + j];
            if (v > mx) { mx = v; am = sub * 40 + j; }   // strict > = first occurrence
        }
        float omx = __shfl_xor(mx, 1);
        int oam = __shfl_xor(am, 1);
        if (sub == 0) {
            if (omx > mx) { mx = omx; am = oam; }   // partner holds higher classes
            float x = p[0], y = p[1], w = p[2], h = p[3], obj = p[4];
            float hw = w * 0.5f, hh = h * 0.5f;
            float score = obj * mx;
            int gi = blockIdx.x * TB + b;
            int pos = base + q;
            if (pos < VMAX) {
                cls_v[pos] = am;
                key_v[pos] = ((ull)(~__float_as_uint(score)) << 32) | (unsigned)gi;
                conf_v[pos] = mx;
                box_v[pos] = make_float4(x - hw, y - hh, x + hw, y + hh);
            }
        }
    }
}

// ---------------- exact alive count (wave-uniform)
template <int L>
__device__ __forceinline__ int exact_alive(ull (&k)[L]) {
    int a = 0;
    #pragma unroll
    for (int j = 0; j < L; j++) a += (int)__popcll(__ballot(k[j] != ~0ULL));
    return a;
}

// ---------------- greedy pick loop; alive refreshed every 8 picks only
template <int L>
__device__ __forceinline__ void pick_loop(ull (&k)[L], float4 (&bx)[L], float (&cf)[L],
                                          int lane, int& alive, int& np,
                                          ull* pkey, float* pconf, int stopAt) {
    while (alive > stopAt) {
        ull lm = k[0]; int lj = 0;
        #pragma unroll
        for (int j = 1; j < L; j++) if (k[j] < lm) { lm = k[j]; lj = j; }
        ull gm = lm;
        #pragma unroll
        for (int off = 32; off; off >>= 1) { ull o = __shfl_xor(gm, off); if (o < gm) gm = o; }
        if (gm == ~0ULL) { alive = 0; break; }
        float4 cb = bx[0]; float cc = cf[0];
        #pragma unroll
        for (int j = 1; j < L; j++) if (j == lj) { cb = bx[j]; cc = cf[j]; }
        ull wb = __ballot(lm == gm);              // unique winner (keys unique)
        int wl2 = (int)__ffsll((long long)wb) - 1;
        cb.x = __shfl(cb.x, wl2); cb.y = __shfl(cb.y, wl2);
        cb.z = __shfl(cb.z, wl2); cb.w = __shfl(cb.w, wl2);
        cc = __shfl(cc, wl2);
        if (lane == 0) { pkey[np] = gm; pconf[np] = cc; }
        np++;
        float a1 = (cb.z - cb.x + 1.0f) * (cb.w - cb.y + 1.0f);
        #pragma unroll
        for (int j = 0; j < L; j++) {
            if (k[j] != ~0ULL) {                  // winner self-kills via IoU=1
                float4 b = bx[j];
                float xx1 = fmaxf(cb.x, b.x), yy1 = fmaxf(cb.y, b.y);
                float xx2 = fminf(cb.z, b.z), yy2 = fminf(cb.w, b.w);
                float iw = xx2 - xx1 + 1.0f, ih = yy2 - yy1 + 1.0f;
                float inter = fmaxf(iw, 0.0f) * fmaxf(ih, 0.0f);
                float a2 = (b.z - b.x + 1.0f) * (b.w - b.y + 1.0f);
                float iou = inter / (a1 + a2 - inter + 1e-16f);
                if (iou > 0.4f) k[j] = ~0ULL;     // NMS_THRES
            }
        }
        if ((np & 7) == 0) alive = exact_alive(k);   // stale-high is safe
    }
}

// ---------------- register compaction LF -> LT via LDS (single wave; alive EXACT)
template <int LF, int LT>
__device__ __forceinline__ void compact_regs(ull (&k)[LF], float4 (&bx)[LF], float (&cf)[LF],
                                             ull (&k2)[LT], float4 (&b2)[LT], float (&c2)[LT],
                                             int lane, int alive,
                                             ull* dk, float4* db, float* dc) {
    int ci = 0;
    #pragma unroll
    for (int j = 0; j < LF; j++) if (k[j] != ~0ULL) ci++;
    int inc = ci;
    for (int off = 1; off < 64; off <<= 1) {
        int o = __shfl_up(inc, off);
        if (lane >= off) inc += o;
    }
    int wp = inc - ci;
    #pragma unroll
    for (int j = 0; j < LF; j++)
        if (k[j] != ~0ULL) { dk[wp] = k[j]; db[wp] = bx[j]; dc[wp] = cf[j]; wp++; }
    #pragma unroll
    for (int j = 0; j < LT; j++) {
        int pos = lane + (j << 6);
        bool ok = pos < alive;
        k2[j] = ok ? dk[pos] : ~0ULL;
        b2[j] = ok ? db[pos] : make_float4(0.f, 0.f, 0.f, 0.f);
        c2[j] = ok ? dc[pos] : 0.0f;
    }
}

// ---------------- stage2+3: per-class compact (8-deep load ILP) + register greedy NMS
__global__ __launch_bounds__(1024) void k_nms(const int* __restrict__ vcount,
                                              const int* __restrict__ cls_v,
                                              const ull* __restrict__ key_v,
                                              const float* __restrict__ conf_v,
                                              const float4* __restrict__ box_v,
                                              ull* __restrict__ pool_key,
                                              float* __restrict__ pool_conf,
                                              int* __restrict__ pool_cls,
                                              int* __restrict__ pool_count) {
    __shared__ ull skey[CAP];
    __shared__ float4 sbox[CAP];
    __shared__ float sconf[CAP];
    __shared__ ull pkey[CAP];
    __shared__ float pconf[CAP];
    __shared__ int s_n;
    const int c = blockIdx.x, t = threadIdx.x, lane = t & 63;
    const int total = min(*vcount, VMAX);
    if (t == 0) s_n = 0;
    for (int p = t; p < CAP; p += 1024) skey[p] = ~0ULL;
    __syncthreads();

    for (int v0 = 0; v0 < total; v0 += 8192) {
        int vals[8];
        #pragma unroll
        for (int qq = 0; qq < 8; qq++) {
            int v = v0 + (qq << 10) + t;
            vals[qq] = (v < total) ? cls_v[v] : -1;   // 8 loads in flight
        }
        #pragma unroll
        for (int qq = 0; qq < 8; qq++) {
            int v = v0 + (qq << 10) + t;
            bool mm = (vals[qq] == c);
            ull bal = __ballot(mm);
            if (bal) {
                int wb;
                if (lane == 0) wb = atomicAdd(&s_n, (int)__popcll(bal));
                wb = __shfl(wb, 0);
                if (mm) {
                    int pos = wb + (int)__popcll(bal & ((1ull << lane) - 1ull));
                    if (pos < CAP) {
                        skey[pos] = key_v[v];
                        sbox[pos] = box_v[v];
                        sconf[pos] = conf_v[v];
                    }
                }
            }
        }
    }
    __syncthreads();
    const int n = min(s_n, CAP);
    if (t >= 64) return;   // wave 0 only from here; no further barriers

    ull k16[16]; float4 b16[16]; float c16[16];
    #pragma unroll
    for (int j = 0; j < 16; j++) {
        int pos = lane + (j << 6);
        k16[j] = skey[pos];
        b16[j] = sbox[pos];
        c16[j] = sconf[pos];
    }
    int alive = n, np = 0;
    pick_loop<16>(k16, b16, c16, lane, alive, np, pkey, pconf, 256);
    alive = exact_alive(k16);
    ull k4[4]; float4 b4[4]; float c4[4];
    compact_regs<16, 4>(k16, b16, c16, k4, b4, c4, lane, alive, skey, sbox, sconf);
    pick_loop<4>(k4, b4, c4, lane, alive, np, pkey, pconf, 64);
    alive = exact_alive(k4);
    ull k1[1]; float4 b1[1]; float c1[1];
    compact_regs<4, 1>(k4, b4, c4, k1, b1, c1, lane, alive, skey, sbox, sconf);
    pick_loop<1>(k1, b1, c1, lane, alive, np, pkey, pconf, 0);

    int npw = min(np, 300);   // exact: a class's 301st pick can't reach global top-300
    int base = 0;
    if (lane == 0 && npw) base = atomicAdd(pool_count, npw);
    base = __shfl(base, 0);
    for (int j = lane; j < npw; j += 64) {
        int pp = base + j;
        if (pp < POOL) {
            ull gm = pkey[j];
            // repack: bit63=0 | 31 score bits | 18 orig_idx | 14 pool_idx
            pool_key[pp] = ((ull)((unsigned)(gm >> 32) & 0x7FFFFFFFu) << 32)
                         | ((gm & 0xFFFFFFFFull) << 14) | (ull)pp;
            pool_conf[pp] = pconf[j];
            pool_cls[pp] = c;
        }
    }
}

// ---------------- single-wave in-register bitonic sort of 512 (8/lane, i = r*64+lane)
__device__ __forceinline__ void bsort512(ull (&x)[8], int lane) {
    #pragma unroll
    for (int k = 2; k <= 512; k <<= 1) {
        #pragma unroll
        for (int j = k >> 1; j >= 64; j >>= 1) {
            const int jr = j >> 6;
            #pragma unroll
            for (int r2 = 0; r2 < 8; r2++) {
                if ((r2 & jr) == 0) {
                    const bool asc = (((r2 << 6) & k) == 0);
                    ull a = x[r2], b = x[r2 | jr];
                    if ((a > b) == asc) { x[r2] = b; x[r2 | jr] = a; }
                }
            }
        }
        #pragma unroll
        for (int j = ((k >> 1) > 32 ? 32 : (k >> 1)); j >= 1; j >>= 1) {
            #pragma unroll
            for (int r2 = 0; r2 < 8; r2++) {
                int i = (r2 << 6) + lane;
                bool asc = ((i & k) == 0);
                ull o = __shfl_xor(x[r2], j);
                bool lower = ((lane & j) == 0);
                ull mn = x[r2] < o ? x[r2] : o;
                ull mx2 = x[r2] < o ? o : x[r2];
                x[r2] = (asc == lower) ? mn : mx2;
            }
        }
    }
}

// ---------------- stage4: prefix-skipped radix-select + single-wave 2-pass sort
__global__ __launch_bounds__(256) void k_final(const ull* __restrict__ pool_key,
                                               const float* __restrict__ pool_conf,
                                               const int* __restrict__ pool_cls,
                                               const int* __restrict__ pool_count,
                                               float* __restrict__ out) {
    __shared__ int s_red[4];
    __shared__ int s_stat[2];
    __shared__ ull s_mm[8];
    __shared__ ull s_buf[512];
    __shared__ unsigned s_cb[512];
    __shared__ unsigned s_cl[512];
    const int t = threadIdx.x, wave = t >> 6, lane = t & 63;
    const int K = min(*pool_count, POOL);
    ull key[32];   // 8192 keys over 256 threads
    #pragma unroll
    for (int j = 0; j < 32; j++) {
        int pos = t + (j << 8);
        key[j] = (pos < K) ? pool_key[pos] : ~0ULL;   // valid keys have bit63=0
    }

    const bool selAll = (K <= 511);
    int bsh = 63; ull p = 0;
    if (!selAll) {
        // min/max over valid keys -> skip the constant high-bit prefix entirely
        ull mn = ~0ULL, mx = 0;
        #pragma unroll
        for (int j = 0; j < 32; j++) {
            ull kk = key[j];
            if (kk != ~0ULL) { if (kk < mn) mn = kk; if (kk > mx) mx = kk; }
        }
        #pragma unroll
        for (int off = 32; off; off >>= 1) {
            ull on = __shfl_xor(mn, off), ox = __shfl_xor(mx, off);
            if (on < mn) mn = on;
            if (ox > mx) mx = ox;
        }
        if (lane == 0) { s_mm[wave * 2] = mn; s_mm[wave * 2 + 1] = mx; }
        __syncthreads();
        mn = min(min(s_mm[0], s_mm[2]), min(s_mm[4], s_mm[6]));
        mx = max(max(s_mm[1], s_mm[3]), max(s_mm[5], s_mm[7]));
        ull diff = mn ^ mx;                      // != 0 (keys unique, K > 511)
        int hb = 63 - __builtin_clzll(diff);     // highest differing bit (<= 62)
        int r = 300, cand = K, b = hb;
        p = mn >> (hb + 1);                      // common prefix of all valid keys
        while (b >= 13 && cand > 212) {
            int c0 = 0;
            #pragma unroll
            for (int j = 0; j < 32; j++) {
                ull kk = key[j];
                if ((kk >> (b + 1)) == p && (((kk >> b) & 1ull) == 0)) c0++;
            }
            #pragma unroll
            for (int off = 32; off; off >>= 1) c0 += __shfl_xor(c0, off);
            if (lane == 0) s_red[wave] = c0;
            __syncthreads();
            if (t == 0) s_stat[0] = s_red[0] + s_red[1] + s_red[2] + s_red[3];
            __syncthreads();
            int cnt0 = s_stat[0];
            if (r <= cnt0) { cand = cnt0; p = p << 1; }
            else { r -= cnt0; cand -= cnt0; p = (p << 1) | 1ull; }
            b--;
        }
        bsh = b + 1;   // select set = {key >> bsh <= p}, size in [300, 511]
    }

    if (t == 0) s_stat[1] = 0;
    __syncthreads();
    int ci = 0;
    #pragma unroll
    for (int j = 0; j < 32; j++) {
        ull kk = key[j];
        bool sel = selAll ? ((kk >> 63) == 0) : ((kk >> bsh) <= p);
        if (sel) ci++;
    }
    int inc = ci;
    for (int off = 1; off < 64; off <<= 1) {
        int o = __shfl_up(inc, off);
        if (lane >= off) inc += o;
    }
    int wtot = __shfl(inc, 63);
    int wbase2 = 0;
    if (lane == 0 && wtot) wbase2 = atomicAdd(&s_stat[1], wtot);
    wbase2 = __shfl(wbase2, 0);
    int wp = wbase2 + inc - ci;
    #pragma unroll
    for (int j = 0; j < 32; j++) {
        ull kk = key[j];
        bool sel = selAll ? ((kk >> 63) == 0) : ((kk >> bsh) <= p);
        if (sel) s_buf[wp++] = kk;
    }
    __syncthreads();
    const int S = s_stat[1];
    for (int i = t; i < 512; i += 256) if (i >= S) s_buf[i] = ~0ULL;
    __syncthreads();
    if (wave != 0) return;   // wave 0 finishes alone; no further barriers

    #pragma clang loop unroll(disable)
    for (int pass = 0; pass < 2; pass++) {
        ull x[8];
        #pragma unroll
        for (int r2 = 0; r2 < 8; r2++) x[r2] = s_buf[(r2 << 6) + lane];
        bsort512(x, lane);
        if (pass == 0) {
            #pragma unroll
            for (int r2 = 0; r2 < 8; r2++) {
                int i = (r2 << 6) + lane;
                ull kk = x[r2];
                ull k2 = ~0ULL;
                if (i < 300 && kk != ~0ULL) {
                    int pidx = (int)(kk & 0x3FFFull);
                    unsigned cb = __float_as_uint(pool_conf[pidx]);
                    unsigned cl = (unsigned)pool_cls[pidx];
                    s_cb[i] = cb; s_cl[i] = cl;
                    k2 = ((ull)(~cb) << 32) | (unsigned)(~i);   // conf desc, rank desc
                }
                s_buf[i] = k2;
            }
        } else {
            #pragma unroll
            for (int r2 = 0; r2 < 8; r2++) {
                int i = (r2 << 6) + lane;
                if (i < 300) {
                    ull kk = x[r2];
                    float idv = 0.0f, pv = 0.0f;
                    if (kk != ~0ULL) {
                        int slot = (int)(~(unsigned)(kk & 0xFFFFFFFFull));
                        pv = __uint_as_float(s_cb[slot]);
                        idv = (float)(int)s_cl[slot];
                    }
                    out[i] = idv;        // ids (1,300)
                    out[300 + i] = pv;   // probs (300,)
                }
            }
        }
    }
}

extern "C" void kernel_launch(void* const* d_in, const int* in_sizes, int n_in,
                              void* d_out, int out_size, void* d_ws, size_t ws_size,
                              hipStream_t stream) {
    const float4* det4 = (const float4*)d_in[0];
    float* out = (float*)d_out;
    char* ws = (char*)d_ws;

    int* vcount = (int*)(ws + 0);
    int* pool_count = (int*)(ws + 4);
    int* cls_v = (int*)(ws + 64);                 // VMAX*4 = 262144
    ull* key_v = (ull*)(ws + 262208);             // VMAX*8 = 524288
    float* conf_v = (float*)(ws + 786496);        // VMAX*4 = 262144
    float4* box_v = (float4*)(ws + 1048640);      // VMAX*16 = 1048576 (16B aligned)
    ull* pool_key = (ull*)(ws + 2097216);         // POOL*8 = 65536
    float* pool_conf = (float*)(ws + 2162752);    // POOL*4 = 32768
    int* pool_cls = (int*)(ws + 2195520);         // POOL*4 = 32768

    k_init<<<1, 64, 0, stream>>>(vcount, pool_count);
    k_stage1<<<NBOX / TB, 256, 0, stream>>>(det4, vcount, cls_v, key_v, conf_v, box_v);
    k_nms<<<NCLS, 1024, 0, stream>>>(vcount, cls_v, key_v, conf_v, box_v,
                                     pool_key, pool_conf, pool_cls, pool_count);
    k_final<<<1, 256, 0, stream>>>(pool_key, pool_conf, pool_cls, pool_count, out);
}

// Round 10
// 193.697 us; speedup vs baseline: 1.6749x; 1.1820x over previous
//
#include <hip/hip_runtime.h>

#pragma clang fp contract(off)

#define NBOX 262144
#define NCLS 80
#define ROWS 85
#define CAP 1024
#define POOL 8192
#define VMAX 65536
#define G 256   // counting-sort segments

typedef unsigned long long ull;

// ---------------- init
__global__ __launch_bounds__(64) void k_init(int* __restrict__ vcount,
                                             int* __restrict__ pool_count) {
    if (threadIdx.x == 0) { *vcount = 0; *pool_count = 0; }
}

// ---------------- stage1: obj-scan + gather class cols for VALID boxes only
__global__ __launch_bounds__(256) void k_stage1(const float* __restrict__ det,
                                                int* __restrict__ vcount,
                                                int* __restrict__ cls_v,
                                                ull* __restrict__ key_v,
                                                float* __restrict__ conf_v,
                                                float4* __restrict__ box_v) {
    __shared__ int s_wl[256];
    __shared__ float s_obj[256];
    __shared__ int wsum[4];
    __shared__ int s_base, s_nv;
    const int t = threadIdx.x, lane = t & 63, wave = t >> 6;
    const int bi = blockIdx.x * 256 + t;

    // phase 1: one obj per thread (line-granular fetch, ~19% of input bytes)
    float obj = det[(size_t)bi * ROWS + 4];
    bool valid = (obj >= 0.8f);   // CONF_THRES
    ull m = __ballot(valid);
    if (lane == 0) wsum[wave] = (int)__popcll(m);
    __syncthreads();
    if (t == 0) {
        int s = 0;
        #pragma unroll
        for (int w = 0; w < 4; w++) { int cc = wsum[w]; wsum[w] = s; s += cc; }
        s_nv = s;
        s_base = s ? atomicAdd(vcount, s) : 0;   // ONE global atomic per block
    }
    __syncthreads();
    if (valid) {
        int r = wsum[wave] + (int)__popcll(m & ((1ull << lane) - 1ull));
        s_wl[r] = t;
        s_obj[r] = obj;
    }
    __syncthreads();
    const int nv = s_nv, base = s_base;

    // phase 2: 16 lanes per valid box; j = k*16 + c covers classes 0..79 exactly
    const int grp = t >> 4, c = t & 15;
    for (int r0 = 0; r0 < nv; r0 += 16) {
        int widx = r0 + grp;
        if (widx < nv) {
            int b = s_wl[widx];
            const float* p = det + (size_t)(blockIdx.x * 256 + b) * ROWS;
            float aux = (c < 5) ? p[c] : 0.0f;    // x y w h obj
            float v0 = p[5 + c];
            float v1 = p[21 + c];
            float v2 = p[37 + c];
            float v3 = p[53 + c];
            float v4 = p[69 + c];
            float mv = v0; int mj = c;
            if (v1 > mv) { mv = v1; mj = 16 + c; }   // ascending j, strict >
            if (v2 > mv) { mv = v2; mj = 32 + c; }
            if (v3 > mv) { mv = v3; mj = 48 + c; }
            if (v4 > mv) { mv = v4; mj = 64 + c; }
            #pragma unroll
            for (int off = 8; off; off >>= 1) {      // group argmax, ties smaller j
                float ov = __shfl_xor(mv, off);
                int oj = __shfl_xor(mj, off);
                if (ov > mv || (ov == mv && oj < mj)) { mv = ov; mj = oj; }
            }
            int gb = lane & 48;                      // group base within wave
            float x = __shfl(aux, gb + 0);
            float y = __shfl(aux, gb + 1);
            float w = __shfl(aux, gb + 2);
            float h = __shfl(aux, gb + 3);
            if (c == 0) {
                float ob = s_obj[widx];
                float score = ob * mv;
                float hw = w * 0.5f, hh = h * 0.5f;
                int gi = blockIdx.x * 256 + b;
                int pos = base + widx;
                if (pos < VMAX) {
                    cls_v[pos] = mj;
                    key_v[pos] = ((ull)(~__float_as_uint(score)) << 32) | (unsigned)gi;
                    conf_v[pos] = mv;
                    box_v[pos] = make_float4(x - hw, y - hh, x + hw, y + hh);
                }
            }
        }
    }
}

// ---------------- counting sort, pass 1: per-segment class histogram
__global__ __launch_bounds__(256) void k_hist(const int* __restrict__ vcount,
                                              const int* __restrict__ cls_v,
                                              int* __restrict__ ghist) {
    __shared__ int h[NCLS];
    const int t = threadIdx.x, g = blockIdx.x;
    if (t < NCLS) h[t] = 0;
    __syncthreads();
    const int total = min(*vcount, VMAX);
    const int seg = (total + G - 1) / G;   // <= 256
    int idx = g * seg + t;
    if (t < seg && idx < total) atomicAdd(&h[cls_v[idx]], 1);
    __syncthreads();
    if (t < NCLS) ghist[t * G + g] = h[t];
}

// ---------------- counting sort, pass 2: offsets (in-place exclusive scans)
__global__ __launch_bounds__(1024) void k_offsets(int* __restrict__ ghist,
                                                  int* __restrict__ cstart,
                                                  int* __restrict__ ccount) {
    __shared__ int ctot[NCLS];
    __shared__ int cst[NCLS];
    const int t = threadIdx.x, wave = t >> 6, lane = t & 63;
    for (int cb = wave; cb < NCLS; cb += 16) {
        int bse = cb * G + lane * 4;
        int v0 = ghist[bse], v1 = ghist[bse + 1], v2 = ghist[bse + 2], v3 = ghist[bse + 3];
        int s = v0 + v1 + v2 + v3;
        int inc = s;
        #pragma unroll
        for (int off = 1; off < 64; off <<= 1) {
            int o = __shfl_up(inc, off);
            if (lane >= off) inc += o;
        }
        int ex = inc - s;
        ghist[bse] = ex;
        ghist[bse + 1] = ex + v0;
        ghist[bse + 2] = ex + v0 + v1;
        ghist[bse + 3] = ex + v0 + v1 + v2;
        if (lane == 63) ctot[cb] = inc;
    }
    __syncthreads();
    if (t == 0) {
        int s = 0;
        for (int cc = 0; cc < NCLS; cc++) { cst[cc] = s; s += ctot[cc]; }
    }
    __syncthreads();
    for (int i = t; i < NCLS * G; i += 1024) ghist[i] += cst[i >> 8];
    if (t < NCLS) { cstart[t] = cst[t]; ccount[t] = ctot[t]; }
}

// ---------------- counting sort, pass 3: scatter into class-contiguous arrays
__global__ __launch_bounds__(256) void k_scatter(const int* __restrict__ vcount,
                                                 const int* __restrict__ cls_v,
                                                 const ull* __restrict__ key_v,
                                                 const float* __restrict__ conf_v,
                                                 const float4* __restrict__ box_v,
                                                 const int* __restrict__ ghist,
                                                 ull* __restrict__ key2,
                                                 float* __restrict__ conf2,
                                                 float4* __restrict__ box2) {
    __shared__ int cnt[NCLS];
    const int t = threadIdx.x, g = blockIdx.x;
    if (t < NCLS) cnt[t] = 0;
    __syncthreads();
    const int total = min(*vcount, VMAX);
    const int seg = (total + G - 1) / G;
    int idx = g * seg + t;
    if (t < seg && idx < total) {
        int cc = cls_v[idx];
        int r = atomicAdd(&cnt[cc], 1);           // within-class order irrelevant
        int dest = ghist[cc * G + g] + r;
        key2[dest] = key_v[idx];
        conf2[dest] = conf_v[idx];
        box2[dest] = box_v[idx];
    }
}

// ---------------- exact alive count (wave-uniform)
template <int L>
__device__ __forceinline__ int exact_alive(ull (&k)[L]) {
    int a = 0;
    #pragma unroll
    for (int j = 0; j < L; j++) a += (int)__popcll(__ballot(k[j] != ~0ULL));
    return a;
}

// ---------------- greedy pick loop; alive refreshed every 8 picks only
template <int L>
__device__ __forceinline__ void pick_loop(ull (&k)[L], float4 (&bx)[L], float (&cf)[L],
                                          int lane, int& alive, int& np,
                                          ull* pkey, float* pconf, int stopAt) {
    while (alive > stopAt) {
        ull lm = k[0]; int lj = 0;
        #pragma unroll
        for (int j = 1; j < L; j++) if (k[j] < lm) { lm = k[j]; lj = j; }
        ull gm = lm;
        #pragma unroll
        for (int off = 32; off; off >>= 1) { ull o = __shfl_xor(gm, off); if (o < gm) gm = o; }
        if (gm == ~0ULL) { alive = 0; break; }
        float4 cb = bx[0]; float cc = cf[0];
        #pragma unroll
        for (int j = 1; j < L; j++) if (j == lj) { cb = bx[j]; cc = cf[j]; }
        ull wb = __ballot(lm == gm);              // unique winner (keys unique)
        int wl2 = (int)__ffsll((long long)wb) - 1;
        cb.x = __shfl(cb.x, wl2); cb.y = __shfl(cb.y, wl2);
        cb.z = __shfl(cb.z, wl2); cb.w = __shfl(cb.w, wl2);
        cc = __shfl(cc, wl2);
        if (lane == 0) { pkey[np] = gm; pconf[np] = cc; }
        np++;
        float a1 = (cb.z - cb.x + 1.0f) * (cb.w - cb.y + 1.0f);
        #pragma unroll
        for (int j = 0; j < L; j++) {
            if (k[j] != ~0ULL) {                  // winner self-kills via IoU=1
                float4 b = bx[j];
                float xx1 = fmaxf(cb.x, b.x), yy1 = fmaxf(cb.y, b.y);
                float xx2 = fminf(cb.z, b.z), yy2 = fminf(cb.w, b.w);
                float iw = xx2 - xx1 + 1.0f, ih = yy2 - yy1 + 1.0f;
                float inter = fmaxf(iw, 0.0f) * fmaxf(ih, 0.0f);
                float a2 = (b.z - b.x + 1.0f) * (b.w - b.y + 1.0f);
                float iou = inter / (a1 + a2 - inter + 1e-16f);
                if (iou > 0.4f) k[j] = ~0ULL;     // NMS_THRES
            }
        }
        if ((np & 7) == 0) alive = exact_alive(k);   // stale-high is safe
    }
}

// ---------------- register compaction LF -> LT via LDS (single wave; alive EXACT)
template <int LF, int LT>
__device__ __forceinline__ void compact_regs(ull (&k)[LF], float4 (&bx)[LF], float (&cf)[LF],
                                             ull (&k2)[LT], float4 (&b2)[LT], float (&c2)[LT],
                                             int lane, int alive,
                                             ull* dk, float4* db, float* dc) {
    int ci = 0;
    #pragma unroll
    for (int j = 0; j < LF; j++) if (k[j] != ~0ULL) ci++;
    int inc = ci;
    for (int off = 1; off < 64; off <<= 1) {
        int o = __shfl_up(inc, off);
        if (lane >= off) inc += o;
    }
    int wp = inc - ci;
    #pragma unroll
    for (int j = 0; j < LF; j++)
        if (k[j] != ~0ULL) { dk[wp] = k[j]; db[wp] = bx[j]; dc[wp] = cf[j]; wp++; }
    #pragma unroll
    for (int j = 0; j < LT; j++) {
        int pos = lane + (j << 6);
        bool ok = pos < alive;
        k2[j] = ok ? dk[pos] : ~0ULL;
        b2[j] = ok ? db[pos] : make_float4(0.f, 0.f, 0.f, 0.f);
        c2[j] = ok ? dc[pos] : 0.0f;
    }
}

// ---------------- stage2+3: single-wave register greedy NMS on contiguous segment
__global__ __launch_bounds__(64) void k_nms(const int* __restrict__ cstart,
                                            const int* __restrict__ ccount,
                                            const ull* __restrict__ key2,
                                            const float* __restrict__ conf2,
                                            const float4* __restrict__ box2,
                                            ull* __restrict__ pool_key,
                                            float* __restrict__ pool_conf,
                                            int* __restrict__ pool_cls,
                                            int* __restrict__ pool_count) {
    __shared__ ull sk[CAP];      // compact_regs scratch
    __shared__ float4 sb[CAP];
    __shared__ float sc[CAP];
    __shared__ ull pkey[CAP];
    __shared__ float pconf[CAP];
    const int c = blockIdx.x, lane = threadIdx.x;
    const int n = min(ccount[c], CAP);
    const int s0 = cstart[c];

    ull k16[16]; float4 b16[16]; float c16[16];
    #pragma unroll
    for (int j = 0; j < 16; j++) {
        int pos = lane + (j << 6);
        bool ok = pos < n;
        k16[j] = ok ? key2[s0 + pos] : ~0ULL;     // coalesced segment loads
        b16[j] = ok ? box2[s0 + pos] : make_float4(0.f, 0.f, 0.f, 0.f);
        c16[j] = ok ? conf2[s0 + pos] : 0.0f;
    }
    int alive = n, np = 0;
    pick_loop<16>(k16, b16, c16, lane, alive, np, pkey, pconf, 256);
    alive = exact_alive(k16);
    ull k4[4]; float4 b4[4]; float c4[4];
    compact_regs<16, 4>(k16, b16, c16, k4, b4, c4, lane, alive, sk, sb, sc);
    pick_loop<4>(k4, b4, c4, lane, alive, np, pkey, pconf, 64);
    alive = exact_alive(k4);
    ull k1[1]; float4 b1[1]; float c1[1];
    compact_regs<4, 1>(k4, b4, c4, k1, b1, c1, lane, alive, sk, sb, sc);
    pick_loop<1>(k1, b1, c1, lane, alive, np, pkey, pconf, 0);

    int npw = min(np, 300);   // exact: a class's 301st pick can't reach global top-300
    int base = 0;
    if (lane == 0 && npw) base = atomicAdd(pool_count, npw);
    base = __shfl(base, 0);
    for (int j = lane; j < npw; j += 64) {
        int pp = base + j;
        if (pp < POOL) {
            ull gm = pkey[j];
            // repack: bit63=0 | 31 score bits | 18 orig_idx | 14 pool_idx
            pool_key[pp] = ((ull)((unsigned)(gm >> 32) & 0x7FFFFFFFu) << 32)
                         | ((gm & 0xFFFFFFFFull) << 14) | (ull)pp;
            pool_conf[pp] = pconf[j];
            pool_cls[pp] = c;
        }
    }
}

// ---------------- single-wave in-register bitonic sort of 512 (8/lane, i = r*64+lane)
__device__ __forceinline__ void bsort512(ull (&x)[8], int lane) {
    #pragma unroll
    for (int k = 2; k <= 512; k <<= 1) {
        #pragma unroll
        for (int j = k >> 1; j >= 64; j >>= 1) {
            const int jr = j >> 6;
            #pragma unroll
            for (int r2 = 0; r2 < 8; r2++) {
                if ((r2 & jr) == 0) {
                    const bool asc = (((r2 << 6) & k) == 0);
                    ull a = x[r2], b = x[r2 | jr];
                    if ((a > b) == asc) { x[r2] = b; x[r2 | jr] = a; }
                }
            }
        }
        #pragma unroll
        for (int j = ((k >> 1) > 32 ? 32 : (k >> 1)); j >= 1; j >>= 1) {
            #pragma unroll
            for (int r2 = 0; r2 < 8; r2++) {
                int i = (r2 << 6) + lane;
                bool asc = ((i & k) == 0);
                ull o = __shfl_xor(x[r2], j);
                bool lower = ((lane & j) == 0);
                ull mn = x[r2] < o ? x[r2] : o;
                ull mx2 = x[r2] < o ? o : x[r2];
                x[r2] = (asc == lower) ? mn : mx2;
            }
        }
    }
}

// ---------------- stage4: prefix-skipped radix-select + single-wave 2-pass sort
__global__ __launch_bounds__(256) void k_final(const ull* __restrict__ pool_key,
                                               const float* __restrict__ pool_conf,
                                               const int* __restrict__ pool_cls,
                                               const int* __restrict__ pool_count,
                                               float* __restrict__ out) {
    __shared__ int s_red[4];
    __shared__ int s_stat[2];
    __shared__ ull s_mm[8];
    __shared__ ull s_buf[512];
    __shared__ unsigned s_cb[512];
    __shared__ unsigned s_cl[512];
    const int t = threadIdx.x, wave = t >> 6, lane = t & 63;
    const int K = min(*pool_count, POOL);
    ull key[32];
    #pragma unroll
    for (int j = 0; j < 32; j++) {
        int pos = t + (j << 8);
        key[j] = (pos < K) ? pool_key[pos] : ~0ULL;
    }

    const bool selAll = (K <= 511);
    int bsh = 63; ull p = 0;
    if (!selAll) {
        ull mn = ~0ULL, mx = 0;
        #pragma unroll
        for (int j = 0; j < 32; j++) {
            ull kk = key[j];
            if (kk != ~0ULL) { if (kk < mn) mn = kk; if (kk > mx) mx = kk; }
        }
        #pragma unroll
        for (int off = 32; off; off >>= 1) {
            ull on = __shfl_xor(mn, off), ox = __shfl_xor(mx, off);
            if (on < mn) mn = on;
            if (ox > mx) mx = ox;
        }
        if (lane == 0) { s_mm[wave * 2] = mn; s_mm[wave * 2 + 1] = mx; }
        __syncthreads();
        mn = min(min(s_mm[0], s_mm[2]), min(s_mm[4], s_mm[6]));
        mx = max(max(s_mm[1], s_mm[3]), max(s_mm[5], s_mm[7]));
        ull diff = mn ^ mx;
        int hb = 63 - __builtin_clzll(diff);
        int r = 300, cand = K, b = hb;
        p = mn >> (hb + 1);
        while (b >= 13 && cand > 212) {
            int c0 = 0;
            #pragma unroll
            for (int j = 0; j < 32; j++) {
                ull kk = key[j];
                if ((kk >> (b + 1)) == p && (((kk >> b) & 1ull) == 0)) c0++;
            }
            #pragma unroll
            for (int off = 32; off; off >>= 1) c0 += __shfl_xor(c0, off);
            if (lane == 0) s_red[wave] = c0;
            __syncthreads();
            if (t == 0) s_stat[0] = s_red[0] + s_red[1] + s_red[2] + s_red[3];
            __syncthreads();
            int cnt0 = s_stat[0];
            if (r <= cnt0) { cand = cnt0; p = p << 1; }
            else { r -= cnt0; cand -= cnt0; p = (p << 1) | 1ull; }
            b--;
        }
        bsh = b + 1;
    }

    if (t == 0) s_stat[1] = 0;
    __syncthreads();
    int ci = 0;
    #pragma unroll
    for (int j = 0; j < 32; j++) {
        ull kk = key[j];
        bool sel = selAll ? ((kk >> 63) == 0) : ((kk >> bsh) <= p);
        if (sel) ci++;
    }
    int inc = ci;
    for (int off = 1; off < 64; off <<= 1) {
        int o = __shfl_up(inc, off);
        if (lane >= off) inc += o;
    }
    int wtot = __shfl(inc, 63);
    int wbase2 = 0;
    if (lane == 0 && wtot) wbase2 = atomicAdd(&s_stat[1], wtot);
    wbase2 = __shfl(wbase2, 0);
    int wp = wbase2 + inc - ci;
    #pragma unroll
    for (int j = 0; j < 32; j++) {
        ull kk = key[j];
        bool sel = selAll ? ((kk >> 63) == 0) : ((kk >> bsh) <= p);
        if (sel) s_buf[wp++] = kk;
    }
    __syncthreads();
    const int S = s_stat[1];
    for (int i = t; i < 512; i += 256) if (i >= S) s_buf[i] = ~0ULL;
    __syncthreads();
    if (wave != 0) return;

    #pragma clang loop unroll(disable)
    for (int pass = 0; pass < 2; pass++) {
        ull x[8];
        #pragma unroll
        for (int r2 = 0; r2 < 8; r2++) x[r2] = s_buf[(r2 << 6) + lane];
        bsort512(x, lane);
        if (pass == 0) {
            #pragma unroll
            for (int r2 = 0; r2 < 8; r2++) {
                int i = (r2 << 6) + lane;
                ull kk = x[r2];
                ull k2 = ~0ULL;
                if (i < 300 && kk != ~0ULL) {
                    int pidx = (int)(kk & 0x3FFFull);
                    unsigned cb = __float_as_uint(pool_conf[pidx]);
                    unsigned cl = (unsigned)pool_cls[pidx];
                    s_cb[i] = cb; s_cl[i] = cl;
                    k2 = ((ull)(~cb) << 32) | (unsigned)(~i);   // conf desc, rank desc
                }
                s_buf[i] = k2;
            }
        } else {
            #pragma unroll
            for (int r2 = 0; r2 < 8; r2++) {
                int i = (r2 << 6) + lane;
                if (i < 300) {
                    ull kk = x[r2];
                    float idv = 0.0f, pv = 0.0f;
                    if (kk != ~0ULL) {
                        int slot = (int)(~(unsigned)(kk & 0xFFFFFFFFull));
                        pv = __uint_as_float(s_cb[slot]);
                        idv = (float)(int)s_cl[slot];
                    }
                    out[i] = idv;        // ids (1,300)
                    out[300 + i] = pv;   // probs (300,)
                }
            }
        }
    }
}

extern "C" void kernel_launch(void* const* d_in, const int* in_sizes, int n_in,
                              void* d_out, int out_size, void* d_ws, size_t ws_size,
                              hipStream_t stream) {
    const float* det = (const float*)d_in[0];
    float* out = (float*)d_out;
    char* ws = (char*)d_ws;

    int* vcount = (int*)(ws + 0);
    int* pool_count = (int*)(ws + 4);
    int* cls_v = (int*)(ws + 64);                 // VMAX*4 = 262144
    ull* key_v = (ull*)(ws + 262208);             // VMAX*8 = 524288
    float* conf_v = (float*)(ws + 786496);        // VMAX*4 = 262144
    float4* box_v = (float4*)(ws + 1048640);      // VMAX*16 = 1048576 (16B aligned)
    ull* pool_key = (ull*)(ws + 2097216);         // POOL*8 = 65536
    float* pool_conf = (float*)(ws + 2162752);    // POOL*4 = 32768
    int* pool_cls = (int*)(ws + 2195520);         // POOL*4 = 32768
    int* ghist = (int*)(ws + 2228288);            // 80*256*4 = 81920
    int* cstart = (int*)(ws + 2310208);           // 320
    int* ccount = (int*)(ws + 2310528);           // 320
    ull* key2 = (ull*)(ws + 2310912);             // 524288
    float* conf2 = (float*)(ws + 2835200);        // 262144
    float4* box2 = (float4*)(ws + 3097344);       // 1048576 (16B aligned)

    k_init<<<1, 64, 0, stream>>>(vcount, pool_count);
    k_stage1<<<NBOX / 256, 256, 0, stream>>>(det, vcount, cls_v, key_v, conf_v, box_v);
    k_hist<<<G, 256, 0, stream>>>(vcount, cls_v, ghist);
    k_offsets<<<1, 1024, 0, stream>>>(ghist, cstart, ccount);
    k_scatter<<<G, 256, 0, stream>>>(vcount, cls_v, key_v, conf_v, box_v, ghist,
                                     key2, conf2, box2);
    k_nms<<<NCLS, 64, 0, stream>>>(cstart, ccount, key2, conf2, box2,
                                   pool_key, pool_conf, pool_cls, pool_count);
    k_final<<<1, 256, 0, stream>>>(pool_key, pool_conf, pool_cls, pool_count, out);
}